// Round 1
// baseline (1233.882 us; speedup 1.0000x reference)
//
#include <hip/hip_runtime.h>
#include <hip/hip_bf16.h>

// Problem constants (fixed by reference setup_inputs)
constexpr int NLAYER = 2;
constexpr int NB = 2;
constexpr int NS = 1024;
constexpr int ND = 512;
constexpr int NH = 32;
constexpr int NF = 2048;
constexpr int NC = 1000;
constexpr float EPS_LN = 1e-5f;

// ---------------------------------------------------------------------------
// Generic fp32 tiled GEMM:  C[b] = alpha * (A[b] @ B[b]) (+bias[N]) (+ReLU)
// Row-major. M,N multiples of 64; K multiple of 16.
// ---------------------------------------------------------------------------
__global__ __launch_bounds__(256) void gemm_nn_kernel(
    const float* __restrict__ A, const float* __restrict__ Bm,
    const float* __restrict__ bias, float* __restrict__ C,
    int M, int N, int K, long sA, long sB, long sC, float alpha, int relu)
{
    const int b = blockIdx.z;
    A += (long)b * sA; Bm += (long)b * sB; C += (long)b * sC;
    const int bm = blockIdx.y * 64, bn = blockIdx.x * 64;
    __shared__ float As[16][65];   // As[k][m]
    __shared__ float Bs[16][64];   // Bs[k][n]
    const int tid = threadIdx.x;
    const int tx = tid & 15, ty = tid >> 4;
    float acc[4][4] = {};
    for (int k0 = 0; k0 < K; k0 += 16) {
        {   // A tile: 64 rows x 16 k, float4 per thread
            int m = tid >> 2;
            int kk = (tid & 3) * 4;
            float4 av = *(const float4*)(A + (long)(bm + m) * K + k0 + kk);
            As[kk + 0][m] = av.x; As[kk + 1][m] = av.y;
            As[kk + 2][m] = av.z; As[kk + 3][m] = av.w;
        }
        {   // B tile: 16 k x 64 n, float4 per thread
            int kk = tid >> 4;
            int n = (tid & 15) * 4;
            float4 bv = *(const float4*)(Bm + (long)(k0 + kk) * N + bn + n);
            *(float4*)&Bs[kk][n] = bv;
        }
        __syncthreads();
        #pragma unroll
        for (int k = 0; k < 16; ++k) {
            float a[4], bb[4];
            #pragma unroll
            for (int i = 0; i < 4; ++i) a[i] = As[k][ty * 4 + i];
            #pragma unroll
            for (int j = 0; j < 4; ++j) bb[j] = Bs[k][tx * 4 + j];
            #pragma unroll
            for (int i = 0; i < 4; ++i)
                #pragma unroll
                for (int j = 0; j < 4; ++j)
                    acc[i][j] += a[i] * bb[j];
        }
        __syncthreads();
    }
    #pragma unroll
    for (int i = 0; i < 4; ++i) {
        int row = bm + ty * 4 + i;
        #pragma unroll
        for (int j = 0; j < 4; ++j) {
            int col = bn + tx * 4 + j;
            float v = acc[i][j] * alpha;
            if (bias) v += bias[col];
            if (relu) v = fmaxf(v, 0.f);
            C[(long)row * N + col] = v;
        }
    }
}

// ---------------------------------------------------------------------------
// NT GEMM for scores: C[b][i][j] = alpha * dot(A[b][i,:], B[b][j,:]) + Add[b][i][j]
// ---------------------------------------------------------------------------
__global__ __launch_bounds__(256) void gemm_nt_addmat_kernel(
    const float* __restrict__ A, const float* __restrict__ Bm,
    const float* __restrict__ Add, float* __restrict__ C,
    int M, int N, int K, long sA, long sB, long sAdd, long sC, float alpha)
{
    const int b = blockIdx.z;
    A += (long)b * sA; Bm += (long)b * sB; Add += (long)b * sAdd; C += (long)b * sC;
    const int bm = blockIdx.y * 64, bn = blockIdx.x * 64;
    __shared__ float As[16][65];   // As[k][m]
    __shared__ float Bs[16][65];   // Bs[k][n]
    const int tid = threadIdx.x;
    const int tx = tid & 15, ty = tid >> 4;
    float acc[4][4] = {};
    for (int k0 = 0; k0 < K; k0 += 16) {
        {
            int m = tid >> 2;
            int kk = (tid & 3) * 4;
            float4 av = *(const float4*)(A + (long)(bm + m) * K + k0 + kk);
            As[kk + 0][m] = av.x; As[kk + 1][m] = av.y;
            As[kk + 2][m] = av.z; As[kk + 3][m] = av.w;
        }
        {
            int n = tid >> 2;
            int kk = (tid & 3) * 4;
            float4 bv = *(const float4*)(Bm + (long)(bn + n) * K + k0 + kk);
            Bs[kk + 0][n] = bv.x; Bs[kk + 1][n] = bv.y;
            Bs[kk + 2][n] = bv.z; Bs[kk + 3][n] = bv.w;
        }
        __syncthreads();
        #pragma unroll
        for (int k = 0; k < 16; ++k) {
            float a[4], bb[4];
            #pragma unroll
            for (int i = 0; i < 4; ++i) a[i] = As[k][ty * 4 + i];
            #pragma unroll
            for (int j = 0; j < 4; ++j) bb[j] = Bs[k][tx * 4 + j];
            #pragma unroll
            for (int i = 0; i < 4; ++i)
                #pragma unroll
                for (int j = 0; j < 4; ++j)
                    acc[i][j] += a[i] * bb[j];
        }
        __syncthreads();
    }
    #pragma unroll
    for (int i = 0; i < 4; ++i) {
        int row = bm + ty * 4 + i;
        #pragma unroll
        for (int j = 0; j < 4; ++j) {
            int col = bn + tx * 4 + j;
            C[(long)row * N + col] = acc[i][j] * alpha + Add[(long)row * N + col];
        }
    }
}

// ---------------------------------------------------------------------------
// Pair-bias precompute: bias[l][b][i][j] = rot+trans+refl MLPs, both layers in
// one pass over pairs (geometry/trig computed once).
// ---------------------------------------------------------------------------
__global__ __launch_bounds__(256) void pair_bias_kernel(
    const float* __restrict__ coords,
    const float* __restrict__ rot_w1, const float* __restrict__ rot_b1,
    const float* __restrict__ rot_w2, const float* __restrict__ rot_b2,
    const float* __restrict__ trans_w1, const float* __restrict__ trans_b1,
    const float* __restrict__ trans_w2, const float* __restrict__ trans_b2,
    const float* __restrict__ refl_w1, const float* __restrict__ refl_b1,
    const float* __restrict__ refl_w2, const float* __restrict__ refl_b2,
    float* __restrict__ bias)
{
    long idx = (long)blockIdx.x * blockDim.x + threadIdx.x;  // over NB*NS*NS
    int j = (int)(idx & (NS - 1));
    long t = idx >> 10;
    int i = (int)(t & (NS - 1));
    int b = (int)(t >> 10);

    float2 ci = ((const float2*)coords)[b * NS + i];
    float2 cj = ((const float2*)coords)[b * NS + j];
    float dx = cj.x - ci.x, dy = cj.y - ci.y;           // rel = coords_j - coords_i
    float dist = sqrtf(dx * dx + dy * dy + 1e-8f);
    float th = atan2f(dy, dx);
    float sn = sinf(th), cs = cosf(th);

    #pragma unroll
    for (int l = 0; l < NLAYER; ++l) {
        const float* rw1 = rot_w1 + l * 3 * NH;
        const float* rb1 = rot_b1 + l * NH;
        const float* rw2 = rot_w2 + l * NH;
        const float* tw1 = trans_w1 + l * 2 * NH;
        const float* tb1 = trans_b1 + l * NH;
        const float* tw2 = trans_w2 + l * NH;
        const float* fw1 = refl_w1 + l * 4 * NH;
        const float* fb1 = refl_b1 + l * NH;
        const float* fw2 = refl_w2 + l * NH;
        float acc = rot_b2[l] + trans_b2[l] + refl_b2[l];
        #pragma unroll 8
        for (int h = 0; h < NH; ++h) {
            float hr = fmaxf(dist * rw1[h] + sn * rw1[NH + h] + cs * rw1[2 * NH + h] + rb1[h], 0.f);
            acc += hr * rw2[h];
            float ht = fmaxf(dx * tw1[h] + dy * tw1[NH + h] + tb1[h], 0.f);
            acc += ht * tw2[h];
            float hf = fmaxf(dx * fw1[h] + dy * fw1[NH + h] - dx * fw1[2 * NH + h] - dy * fw1[3 * NH + h] + fb1[h], 0.f);
            acc += hf * fw2[h];
        }
        bias[(long)l * ((long)NB * NS * NS) + idx] = acc;
    }
}

// ---------------------------------------------------------------------------
// Row softmax over last dim (NS=1024), one block per row, 256 threads x float4
// ---------------------------------------------------------------------------
__global__ __launch_bounds__(256) void softmax_kernel(float* __restrict__ sc)
{
    float* p = sc + (long)blockIdx.x * NS;
    const int tid = threadIdx.x;
    float4 v = ((float4*)p)[tid];
    float m = fmaxf(fmaxf(v.x, v.y), fmaxf(v.z, v.w));
    #pragma unroll
    for (int off = 32; off; off >>= 1) m = fmaxf(m, __shfl_xor(m, off));
    __shared__ float red[4], red2[4];
    int wid = tid >> 6;
    if ((tid & 63) == 0) red[wid] = m;
    __syncthreads();
    m = fmaxf(fmaxf(red[0], red[1]), fmaxf(red[2], red[3]));
    v.x = __expf(v.x - m); v.y = __expf(v.y - m);
    v.z = __expf(v.z - m); v.w = __expf(v.w - m);
    float s = v.x + v.y + v.z + v.w;
    #pragma unroll
    for (int off = 32; off; off >>= 1) s += __shfl_xor(s, off);
    if ((tid & 63) == 0) red2[wid] = s;
    __syncthreads();
    s = red2[0] + red2[1] + red2[2] + red2[3];
    float inv = 1.f / s;
    v.x *= inv; v.y *= inv; v.z *= inv; v.w *= inv;
    ((float4*)p)[tid] = v;
}

// ---------------------------------------------------------------------------
// out = LayerNorm(x (+ res)) * g + b ; one block per row of ND=512, in-place OK
// ---------------------------------------------------------------------------
__global__ __launch_bounds__(256) void add_ln_kernel(
    const float* __restrict__ x, const float* __restrict__ res,
    const float* __restrict__ g, const float* __restrict__ bt,
    float* __restrict__ out)
{
    long row = blockIdx.x;
    const int tid = threadIdx.x;
    float2 xv = ((const float2*)(x + row * ND))[tid];
    if (res) {
        float2 rv = ((const float2*)(res + row * ND))[tid];
        xv.x += rv.x; xv.y += rv.y;
    }
    float s = xv.x + xv.y;
    float ss = xv.x * xv.x + xv.y * xv.y;
    #pragma unroll
    for (int off = 32; off; off >>= 1) {
        s += __shfl_xor(s, off);
        ss += __shfl_xor(ss, off);
    }
    __shared__ float rs[4], rss[4];
    int wid = tid >> 6;
    if ((tid & 63) == 0) { rs[wid] = s; rss[wid] = ss; }
    __syncthreads();
    s = rs[0] + rs[1] + rs[2] + rs[3];
    ss = rss[0] + rss[1] + rss[2] + rss[3];
    float mu = s * (1.f / ND);
    float var = ss * (1.f / ND) - mu * mu;
    float inv = rsqrtf(var + EPS_LN);
    float2 gv = ((const float2*)g)[tid];
    float2 bv = ((const float2*)bt)[tid];
    float2 o;
    o.x = (xv.x - mu) * inv * gv.x + bv.x;
    o.y = (xv.y - mu) * inv * gv.y + bv.y;
    ((float2*)(out + row * ND))[tid] = o;
}

// pooled[b][d] = mean_s x[b][s][d]
__global__ __launch_bounds__(256) void pool_kernel(
    const float* __restrict__ x, float* __restrict__ pooled)
{
    int d = blockIdx.x * 256 + threadIdx.x;
    int b = blockIdx.y;
    float s = 0.f;
    for (int i = 0; i < NS; ++i) s += x[((long)b * NS + i) * ND + d];
    pooled[b * ND + d] = s * (1.f / NS);
}

// out[b][c] = pooled[b] . fc_w[:,c] + fc_b[c]
__global__ __launch_bounds__(256) void fc_kernel(
    const float* __restrict__ pooled, const float* __restrict__ w,
    const float* __restrict__ bias, float* __restrict__ out)
{
    int c = blockIdx.x * 256 + threadIdx.x;
    int b = blockIdx.y;
    if (c >= NC) return;
    float acc = bias[c];
    const float* p = pooled + b * ND;
    for (int d = 0; d < ND; ++d) acc += p[d] * w[(long)d * NC + c];
    out[(long)b * NC + c] = acc;
}

// ---------------------------------------------------------------------------
extern "C" void kernel_launch(void* const* d_in, const int* in_sizes, int n_in,
                              void* d_out, int out_size, void* d_ws, size_t ws_size,
                              hipStream_t stream)
{
    const float* x_in   = (const float*)d_in[0];
    const float* coords = (const float*)d_in[1];
    const float* Wq     = (const float*)d_in[2];
    const float* Wk     = (const float*)d_in[3];
    const float* Wv     = (const float*)d_in[4];
    const float* rot_w1 = (const float*)d_in[5];
    const float* rot_b1 = (const float*)d_in[6];
    const float* rot_w2 = (const float*)d_in[7];
    const float* rot_b2 = (const float*)d_in[8];
    const float* trans_w1 = (const float*)d_in[9];
    const float* trans_b1 = (const float*)d_in[10];
    const float* trans_w2 = (const float*)d_in[11];
    const float* trans_b2 = (const float*)d_in[12];
    const float* refl_w1 = (const float*)d_in[13];
    const float* refl_b1 = (const float*)d_in[14];
    const float* refl_w2 = (const float*)d_in[15];
    const float* refl_b2 = (const float*)d_in[16];
    const float* ln1_g = (const float*)d_in[17];
    const float* ln1_b = (const float*)d_in[18];
    const float* ffn_w1 = (const float*)d_in[19];
    const float* ffn_b1 = (const float*)d_in[20];
    const float* ffn_w2 = (const float*)d_in[21];
    const float* ffn_b2 = (const float*)d_in[22];
    const float* ln2_g = (const float*)d_in[23];
    const float* ln2_b = (const float*)d_in[24];
    const float* lnf_g = (const float*)d_in[25];
    const float* lnf_b = (const float*)d_in[26];
    const float* fc_w = (const float*)d_in[27];
    const float* fc_b = (const float*)d_in[28];
    float* out = (float*)d_out;

    // workspace layout (floats)
    const long XSZ = (long)NB * NS * ND;      // 1M
    const long SSZ = (long)NB * NS * NS;      // 2M
    float* ws = (float*)d_ws;
    float* x_cur = ws;                 ws += XSZ;
    float* q     = ws;                 ws += XSZ;
    float* k     = ws;                 ws += XSZ;
    float* v     = ws;                 ws += XSZ;
    float* sc    = ws;                 ws += SSZ;          // scores / attn
    float* bias2 = ws;                 ws += (long)NLAYER * SSZ;
    float* ao    = ws;                 ws += XSZ;          // attn_out / ffn_out
    float* hf    = ws;                 ws += (long)NB * NS * NF;
    float* pooled = ws;                ws += (long)NB * ND;

    const long SD = (long)NS * ND, SS = (long)NS * NS;
    const float inv_scale = 1.0f / sqrtf((float)ND);

    // x_cur = x
    hipMemcpyAsync(x_cur, x_in, sizeof(float) * XSZ, hipMemcpyDeviceToDevice, stream);

    // pair biases for both layers
    pair_bias_kernel<<<dim3((NB * NS * NS) / 256), 256, 0, stream>>>(
        coords, rot_w1, rot_b1, rot_w2, rot_b2,
        trans_w1, trans_b1, trans_w2, trans_b2,
        refl_w1, refl_b1, refl_w2, refl_b2, bias2);

    for (int l = 0; l < NLAYER; ++l) {
        const float* wq = Wq + (long)l * ND * ND;
        const float* wk = Wk + (long)l * ND * ND;
        const float* wv = Wv + (long)l * ND * ND;

        // Q,K,V : [2048,512] @ [512,512]
        gemm_nn_kernel<<<dim3(ND / 64, (NB * NS) / 64, 1), 256, 0, stream>>>(
            x_cur, wq, nullptr, q, NB * NS, ND, ND, 0, 0, 0, 1.f, 0);
        gemm_nn_kernel<<<dim3(ND / 64, (NB * NS) / 64, 1), 256, 0, stream>>>(
            x_cur, wk, nullptr, k, NB * NS, ND, ND, 0, 0, 0, 1.f, 0);
        gemm_nn_kernel<<<dim3(ND / 64, (NB * NS) / 64, 1), 256, 0, stream>>>(
            x_cur, wv, nullptr, v, NB * NS, ND, ND, 0, 0, 0, 1.f, 0);

        // scores = Q K^T / sqrt(D) + bias[l]
        gemm_nt_addmat_kernel<<<dim3(NS / 64, NS / 64, NB), 256, 0, stream>>>(
            q, k, bias2 + (long)l * SSZ, sc, NS, NS, ND, SD, SD, SS, SS, inv_scale);

        // softmax rows
        softmax_kernel<<<dim3(NB * NS), 256, 0, stream>>>(sc);

        // attn_out = P @ V  (batched)
        gemm_nn_kernel<<<dim3(ND / 64, NS / 64, NB), 256, 0, stream>>>(
            sc, v, nullptr, ao, NS, ND, NS, SS, SD, SD, 1.f, 0);

        // x = LN(x + attn_out)
        add_ln_kernel<<<dim3(NB * NS), 256, 0, stream>>>(
            x_cur, ao, ln1_g + (long)l * ND, ln1_b + (long)l * ND, x_cur);

        // FFN
        gemm_nn_kernel<<<dim3(NF / 64, (NB * NS) / 64, 1), 256, 0, stream>>>(
            x_cur, ffn_w1 + (long)l * ND * NF, ffn_b1 + (long)l * NF, hf,
            NB * NS, NF, ND, 0, 0, 0, 1.f, 1);
        gemm_nn_kernel<<<dim3(ND / 64, (NB * NS) / 64, 1), 256, 0, stream>>>(
            hf, ffn_w2 + (long)l * NF * ND, ffn_b2 + (long)l * ND, ao,
            NB * NS, ND, NF, 0, 0, 0, 1.f, 0);

        // x = LN(x + ffn)
        add_ln_kernel<<<dim3(NB * NS), 256, 0, stream>>>(
            x_cur, ao, ln2_g + (long)l * ND, ln2_b + (long)l * ND, x_cur);
    }

    // final LN (no residual)
    add_ln_kernel<<<dim3(NB * NS), 256, 0, stream>>>(
        x_cur, nullptr, lnf_g, lnf_b, x_cur);

    // pooled = mean over S
    pool_kernel<<<dim3(ND / 256, NB), 256, 0, stream>>>(x_cur, pooled);

    // out = pooled @ fc_w + fc_b
    fc_kernel<<<dim3((NC + 255) / 256, NB), 256, 0, stream>>>(pooled, fc_w, fc_b, out);
}

// Round 2
// 464.533 us; speedup vs baseline: 2.6562x; 2.6562x over previous
//
#include <hip/hip_runtime.h>
#include <hip/hip_bf16.h>

using bf16 = __hip_bfloat16;
typedef __attribute__((ext_vector_type(8))) short short8;
typedef __attribute__((ext_vector_type(4))) float f32x4;

constexpr int NLAYER = 2;
constexpr int NB = 2;
constexpr int NS = 1024;
constexpr int ND = 512;
constexpr int NH = 32;
constexpr int NF = 2048;
constexpr int NC = 1000;
constexpr float EPS_LN = 1e-5f;

__device__ inline unsigned short f2bfu(float x) {
    union { bf16 h; unsigned short u; } c;
    c.h = __float2bfloat16(x);
    return c.u;
}

#define GLOAD16(gp, lp) __builtin_amdgcn_global_load_lds( \
    (const __attribute__((address_space(1))) void*)(gp),  \
    (__attribute__((address_space(3))) void*)(lp), 16, 0, 0)

// ---------------------------------------------------------------------------
// bf16 MFMA GEMM, C = A[MxK] * B^T[NxK] (+bias) (+ReLU | scores-epilogue)
// BM x BN tile, 4 waves (2x2), BK=32, mfma_f32_16x16x32_bf16.
// ---------------------------------------------------------------------------
template<int BM, int BN, bool OUTBF, bool RELU, bool SCORES>
__global__ __launch_bounds__(256) void mfma_gemm(
    const bf16* __restrict__ A, const bf16* __restrict__ B,
    const float* __restrict__ bias, void* __restrict__ Cout,
    const float* __restrict__ table,
    int K, int lda, int ldb, int ldc,
    long sA, long sB, long sC, float alpha)
{
    const int bz = blockIdx.z;
    A += (long)bz * sA;
    B += (long)bz * sB;
    const int bm = blockIdx.y * BM, bn = blockIdx.x * BN;
    __shared__ bf16 As[BM * 32], Bs[BN * 32];
    const int tid = threadIdx.x, lane = tid & 63, wv = tid >> 6;
    const int wr = (wv >> 1) * (BM / 2), wc = (wv & 1) * (BN / 2);
    constexpr int FM = BM / 32, FN = BN / 32;
    f32x4 acc[FM][FN] = {};
    const int r_a = tid >> 2;           // staging row (sweep adds 64)
    const int ko = (tid & 3) * 8;       // staging k offset (elems)
    const short8* Asv = (const short8*)As;
    const short8* Bsv = (const short8*)Bs;

    for (int k0 = 0; k0 < K; k0 += 32) {
        #pragma unroll
        for (int c = 0; c < BM / 64; ++c)
            GLOAD16(A + (long)(bm + r_a + c * 64) * lda + k0 + ko,
                    As + c * 2048 + wv * 512);
        #pragma unroll
        for (int c = 0; c < BN / 64; ++c)
            GLOAD16(B + (long)(bn + r_a + c * 64) * ldb + k0 + ko,
                    Bs + c * 2048 + wv * 512);
        __syncthreads();
        short8 af[FM], bfr[FN];
        #pragma unroll
        for (int m = 0; m < FM; ++m)
            af[m] = Asv[(wr + m * 16 + (lane & 15)) * 4 + (lane >> 4)];
        #pragma unroll
        for (int n = 0; n < FN; ++n)
            bfr[n] = Bsv[(wc + n * 16 + (lane & 15)) * 4 + (lane >> 4)];
        #pragma unroll
        for (int m = 0; m < FM; ++m)
            #pragma unroll
            for (int n = 0; n < FN; ++n)
                acc[m][n] = __builtin_amdgcn_mfma_f32_16x16x32_bf16(
                    af[m], bfr[n], acc[m][n], 0, 0, 0);
        __syncthreads();
    }

    const int er = (lane >> 4) * 4, ec = lane & 15;
    #pragma unroll
    for (int m = 0; m < FM; ++m) {
        #pragma unroll
        for (int n = 0; n < FN; ++n) {
            const int row0 = bm + wr + m * 16 + er;
            const int col  = bn + wc + n * 16 + ec;
            const float bv = bias ? bias[col] : 0.f;
            #pragma unroll
            for (int e = 0; e < 4; ++e) {
                const int row = row0 + e;
                float v = acc[m][n][e];
                if (SCORES) {
                    int di = (col >> 5) - (row >> 5) + 31;
                    int dj = (col & 31) - (row & 31) + 31;
                    v = v * alpha + table[di * 63 + dj];
                } else {
                    v += bv;
                    if (RELU) v = fmaxf(v, 0.f);
                }
                if (OUTBF)
                    ((bf16*)Cout)[bz * sC + (long)row * ldc + col] = __float2bfloat16(v);
                else
                    ((float*)Cout)[bz * sC + (long)row * ldc + col] = v;
            }
        }
    }
}

// ---------------------------------------------------------------------------
// Transpose + f32->bf16 convert: dst[C][R] = (bf16) src[R][C], batched over z
// ---------------------------------------------------------------------------
__global__ __launch_bounds__(256) void tconv_f32_kernel(
    const float* __restrict__ src, bf16* __restrict__ dst,
    int R, int C, long sS, long sD)
{
    src += (long)blockIdx.z * sS;
    dst += (long)blockIdx.z * sD;
    __shared__ float t[32][33];
    const int c0 = blockIdx.x * 32, r0 = blockIdx.y * 32;
    const int lx = threadIdx.x & 31, ly = threadIdx.x >> 5;
    for (int rr = ly; rr < 32; rr += 8)
        t[rr][lx] = src[(long)(r0 + rr) * C + c0 + lx];
    __syncthreads();
    for (int cc = ly; cc < 32; cc += 8)
        dst[(long)(c0 + cc) * R + r0 + lx] = __float2bfloat16(t[lx][cc]);
}

// bf16 transpose with leading dims (for V^T), batched over z
__global__ __launch_bounds__(256) void tbf_kernel(
    const bf16* __restrict__ src, bf16* __restrict__ dst,
    int ldsrc, int lddst, long sS, long sD)
{
    src += (long)blockIdx.z * sS;
    dst += (long)blockIdx.z * sD;
    __shared__ bf16 t[32][33];
    const int c0 = blockIdx.x * 32, r0 = blockIdx.y * 32;
    const int lx = threadIdx.x & 31, ly = threadIdx.x >> 5;
    for (int rr = ly; rr < 32; rr += 8)
        t[rr][lx] = src[(long)(r0 + rr) * ldsrc + c0 + lx];
    __syncthreads();
    for (int cc = ly; cc < 32; cc += 8)
        dst[(long)(c0 + cc) * lddst + r0 + lx] = t[lx][cc];
}

// x_cur = x_in (f32), xb = bf16(x_in)
__global__ __launch_bounds__(256) void xcopy_kernel(
    const float* __restrict__ xin, float* __restrict__ xc, bf16* __restrict__ xb)
{
    long i = (long)blockIdx.x * 256 + threadIdx.x;
    float4 v = ((const float4*)xin)[i];
    ((float4*)xc)[i] = v;
    uint2 o;
    o.x = (unsigned)f2bfu(v.x) | ((unsigned)f2bfu(v.y) << 16);
    o.y = (unsigned)f2bfu(v.z) | ((unsigned)f2bfu(v.w) << 16);
    ((uint2*)xb)[i] = o;
}

// ---------------------------------------------------------------------------
// Pair-bias table: coords form an exact 32x32 grid, so rel=(dxy) depends only
// on (da,db) in [-31,31]^2 -> 63x63 table per layer.
// ---------------------------------------------------------------------------
__global__ __launch_bounds__(256) void bias_table_kernel(
    const float* __restrict__ coords,
    const float* __restrict__ rot_w1, const float* __restrict__ rot_b1,
    const float* __restrict__ rot_w2, const float* __restrict__ rot_b2,
    const float* __restrict__ trans_w1, const float* __restrict__ trans_b1,
    const float* __restrict__ trans_w2, const float* __restrict__ trans_b2,
    const float* __restrict__ refl_w1, const float* __restrict__ refl_b1,
    const float* __restrict__ refl_w2, const float* __restrict__ refl_b2,
    float* __restrict__ table)
{
    int idx = blockIdx.x * 256 + threadIdx.x;
    if (idx >= 63 * 63) return;
    int da = idx / 63 - 31, db = idx % 63 - 31;
    int ai = da < 0 ? -da : 0, bi = db < 0 ? -db : 0;
    int i = ai * 32 + bi, j = (ai + da) * 32 + (bi + db);
    float2 ci = ((const float2*)coords)[i];
    float2 cj = ((const float2*)coords)[j];
    float dx = cj.x - ci.x, dy = cj.y - ci.y;
    float dist = sqrtf(dx * dx + dy * dy + 1e-8f);
    float th = atan2f(dy, dx);
    float sn = sinf(th), cs = cosf(th);

    #pragma unroll
    for (int l = 0; l < NLAYER; ++l) {
        const float* rw1 = rot_w1 + l * 3 * NH;
        const float* rb1 = rot_b1 + l * NH;
        const float* rw2 = rot_w2 + l * NH;
        const float* tw1 = trans_w1 + l * 2 * NH;
        const float* tb1 = trans_b1 + l * NH;
        const float* tw2 = trans_w2 + l * NH;
        const float* fw1 = refl_w1 + l * 4 * NH;
        const float* fb1 = refl_b1 + l * NH;
        const float* fw2 = refl_w2 + l * NH;
        float acc = rot_b2[l] + trans_b2[l] + refl_b2[l];
        #pragma unroll 8
        for (int h = 0; h < NH; ++h) {
            float hr = fmaxf(dist * rw1[h] + sn * rw1[NH + h] + cs * rw1[2 * NH + h] + rb1[h], 0.f);
            acc += hr * rw2[h];
            float ht = fmaxf(dx * tw1[h] + dy * tw1[NH + h] + tb1[h], 0.f);
            acc += ht * tw2[h];
            float hf = fmaxf(dx * fw1[h] + dy * fw1[NH + h] - dx * fw1[2 * NH + h] - dy * fw1[3 * NH + h] + fb1[h], 0.f);
            acc += hf * fw2[h];
        }
        table[l * 3969 + idx] = acc;
    }
}

// ---------------------------------------------------------------------------
// Row softmax over NS=1024 (f32 in) -> bf16 out
// ---------------------------------------------------------------------------
__global__ __launch_bounds__(256) void softmax_kernel(
    const float* __restrict__ sc, bf16* __restrict__ P)
{
    const float* p = sc + (long)blockIdx.x * NS;
    const int tid = threadIdx.x;
    float4 v = ((const float4*)p)[tid];
    float m = fmaxf(fmaxf(v.x, v.y), fmaxf(v.z, v.w));
    #pragma unroll
    for (int off = 32; off; off >>= 1) m = fmaxf(m, __shfl_xor(m, off));
    __shared__ float red[4], red2[4];
    int wid = tid >> 6;
    if ((tid & 63) == 0) red[wid] = m;
    __syncthreads();
    m = fmaxf(fmaxf(red[0], red[1]), fmaxf(red[2], red[3]));
    v.x = __expf(v.x - m); v.y = __expf(v.y - m);
    v.z = __expf(v.z - m); v.w = __expf(v.w - m);
    float s = v.x + v.y + v.z + v.w;
    #pragma unroll
    for (int off = 32; off; off >>= 1) s += __shfl_xor(s, off);
    if ((tid & 63) == 0) red2[wid] = s;
    __syncthreads();
    s = red2[0] + red2[1] + red2[2] + red2[3];
    float inv = 1.f / s;
    uint2 o;
    o.x = (unsigned)f2bfu(v.x * inv) | ((unsigned)f2bfu(v.y * inv) << 16);
    o.y = (unsigned)f2bfu(v.z * inv) | ((unsigned)f2bfu(v.w * inv) << 16);
    ((uint2*)(P + (long)blockIdx.x * NS))[tid] = o;
}

// ---------------------------------------------------------------------------
// out = LayerNorm(x (+res)); also writes bf16 copy if outb != null
// ---------------------------------------------------------------------------
__global__ __launch_bounds__(256) void add_ln_kernel(
    const float* __restrict__ x, const float* __restrict__ res,
    const float* __restrict__ g, const float* __restrict__ bt,
    float* __restrict__ out, bf16* __restrict__ outb)
{
    long row = blockIdx.x;
    const int tid = threadIdx.x;
    float2 xv = ((const float2*)(x + row * ND))[tid];
    if (res) {
        float2 rv = ((const float2*)(res + row * ND))[tid];
        xv.x += rv.x; xv.y += rv.y;
    }
    float s = xv.x + xv.y;
    float ss = xv.x * xv.x + xv.y * xv.y;
    #pragma unroll
    for (int off = 32; off; off >>= 1) {
        s += __shfl_xor(s, off);
        ss += __shfl_xor(ss, off);
    }
    __shared__ float rs[4], rss[4];
    int wid = tid >> 6;
    if ((tid & 63) == 0) { rs[wid] = s; rss[wid] = ss; }
    __syncthreads();
    s = rs[0] + rs[1] + rs[2] + rs[3];
    ss = rss[0] + rss[1] + rss[2] + rss[3];
    float mu = s * (1.f / ND);
    float var = ss * (1.f / ND) - mu * mu;
    float inv = rsqrtf(var + EPS_LN);
    float2 gv = ((const float2*)g)[tid];
    float2 bv = ((const float2*)bt)[tid];
    float2 o;
    o.x = (xv.x - mu) * inv * gv.x + bv.x;
    o.y = (xv.y - mu) * inv * gv.y + bv.y;
    ((float2*)(out + row * ND))[tid] = o;
    if (outb)
        ((unsigned int*)(outb + row * ND))[tid] =
            (unsigned)f2bfu(o.x) | ((unsigned)f2bfu(o.y) << 16);
}

__global__ __launch_bounds__(256) void pool_kernel(
    const float* __restrict__ x, float* __restrict__ pooled)
{
    int d = blockIdx.x * 256 + threadIdx.x;
    int b = blockIdx.y;
    float s = 0.f;
    for (int i = 0; i < NS; ++i) s += x[((long)b * NS + i) * ND + d];
    pooled[b * ND + d] = s * (1.f / NS);
}

__global__ __launch_bounds__(256) void fc_kernel(
    const float* __restrict__ pooled, const float* __restrict__ w,
    const float* __restrict__ bias, float* __restrict__ out)
{
    int c = blockIdx.x * 256 + threadIdx.x;
    int b = blockIdx.y;
    if (c >= NC) return;
    float acc = bias[c];
    const float* p = pooled + b * ND;
    for (int d = 0; d < ND; ++d) acc += p[d] * w[(long)d * NC + c];
    out[(long)b * NC + c] = acc;
}

// ---------------------------------------------------------------------------
extern "C" void kernel_launch(void* const* d_in, const int* in_sizes, int n_in,
                              void* d_out, int out_size, void* d_ws, size_t ws_size,
                              hipStream_t stream)
{
    const float* x_in   = (const float*)d_in[0];
    const float* coords = (const float*)d_in[1];
    const float* Wq     = (const float*)d_in[2];
    const float* Wk     = (const float*)d_in[3];
    const float* Wv     = (const float*)d_in[4];
    const float* rot_w1 = (const float*)d_in[5];
    const float* rot_b1 = (const float*)d_in[6];
    const float* rot_w2 = (const float*)d_in[7];
    const float* rot_b2 = (const float*)d_in[8];
    const float* trans_w1 = (const float*)d_in[9];
    const float* trans_b1 = (const float*)d_in[10];
    const float* trans_w2 = (const float*)d_in[11];
    const float* trans_b2 = (const float*)d_in[12];
    const float* refl_w1 = (const float*)d_in[13];
    const float* refl_b1 = (const float*)d_in[14];
    const float* refl_w2 = (const float*)d_in[15];
    const float* refl_b2 = (const float*)d_in[16];
    const float* ln1_g = (const float*)d_in[17];
    const float* ln1_b = (const float*)d_in[18];
    const float* ffn_w1 = (const float*)d_in[19];
    const float* ffn_b1 = (const float*)d_in[20];
    const float* ffn_w2 = (const float*)d_in[21];
    const float* ffn_b2 = (const float*)d_in[22];
    const float* ln2_g = (const float*)d_in[23];
    const float* ln2_b = (const float*)d_in[24];
    const float* lnf_g = (const float*)d_in[25];
    const float* lnf_b = (const float*)d_in[26];
    const float* fc_w = (const float*)d_in[27];
    const float* fc_b = (const float*)d_in[28];
    float* out = (float*)d_out;

    const long XSZ = (long)NB * NS * ND;   // 1M elems
    const long SSZ = (long)NB * NS * NS;   // 2M elems

    char* wp = (char*)d_ws;
    auto alloc = [&](long bytes) -> char* {
        char* p = wp; wp += (bytes + 255) & ~(long)255; return p;
    };
    float* x_cur  = (float*)alloc(XSZ * 4);
    bf16*  xb     = (bf16*)alloc(XSZ * 2);
    bf16*  qkv    = (bf16*)alloc((long)NB * NS * 1536 * 2);
    bf16*  vT     = (bf16*)alloc((long)NB * ND * NS * 2);
    float* sc     = (float*)alloc(SSZ * 4);
    bf16*  pb     = (bf16*)alloc(SSZ * 2);
    float* ao     = (float*)alloc(XSZ * 4);
    bf16*  hfb    = (bf16*)alloc((long)NB * NS * NF * 2);
    bf16*  wqkvT  = (bf16*)alloc((long)NLAYER * 3 * ND * ND * 2);
    bf16*  w1T    = (bf16*)alloc((long)NLAYER * NF * ND * 2);
    bf16*  w2T    = (bf16*)alloc((long)NLAYER * ND * NF * 2);
    float* table  = (float*)alloc((long)NLAYER * 3969 * 4);
    float* pooled = (float*)alloc((long)NB * ND * 4);

    const float inv_scale = 1.0f / sqrtf((float)ND);
    const long QKVLD = 1536;

    // ---- weight transposes (batched over layers via z) ----
    tconv_f32_kernel<<<dim3(16, 16, NLAYER), 256, 0, stream>>>(
        Wq, wqkvT + 0,            ND, ND, (long)ND * ND, (long)3 * ND * ND);
    tconv_f32_kernel<<<dim3(16, 16, NLAYER), 256, 0, stream>>>(
        Wk, wqkvT + (long)ND * ND, ND, ND, (long)ND * ND, (long)3 * ND * ND);
    tconv_f32_kernel<<<dim3(16, 16, NLAYER), 256, 0, stream>>>(
        Wv, wqkvT + (long)2 * ND * ND, ND, ND, (long)ND * ND, (long)3 * ND * ND);
    tconv_f32_kernel<<<dim3(64, 16, NLAYER), 256, 0, stream>>>(
        ffn_w1, w1T, ND, NF, (long)ND * NF, (long)NF * ND);
    tconv_f32_kernel<<<dim3(16, 64, NLAYER), 256, 0, stream>>>(
        ffn_w2, w2T, NF, ND, (long)NF * ND, (long)ND * NF);

    xcopy_kernel<<<dim3((int)(XSZ / 1024)), 256, 0, stream>>>(x_in, x_cur, xb);

    bias_table_kernel<<<dim3(16), 256, 0, stream>>>(
        coords, rot_w1, rot_b1, rot_w2, rot_b2,
        trans_w1, trans_b1, trans_w2, trans_b2,
        refl_w1, refl_b1, refl_w2, refl_b2, table);

    for (int l = 0; l < NLAYER; ++l) {
        // QKV fused: [2048,512] @ [1536,512]^T -> qkv bf16 [2048,1536]
        mfma_gemm<128, 128, true, false, false>
            <<<dim3(1536 / 128, (NB * NS) / 128, 1), 256, 0, stream>>>(
            xb, wqkvT + (long)l * 3 * ND * ND, nullptr, qkv, nullptr,
            ND, ND, ND, QKVLD, 0, 0, 0, 0.f);

        // V^T per batch: [1024,512] -> [512,1024]
        tbf_kernel<<<dim3(ND / 32, NS / 32, NB), 256, 0, stream>>>(
            qkv + 2 * ND, vT, QKVLD, NS, (long)NS * QKVLD, (long)ND * NS);

        // scores = Q K^T * inv_scale + table gather, f32 out
        mfma_gemm<128, 128, false, false, true>
            <<<dim3(NS / 128, NS / 128, NB), 256, 0, stream>>>(
            qkv, qkv + ND, nullptr, sc, table + (long)l * 3969,
            ND, QKVLD, QKVLD, NS, (long)NS * QKVLD, (long)NS * QKVLD,
            (long)NS * NS, inv_scale);

        softmax_kernel<<<dim3(NB * NS), 256, 0, stream>>>(sc, pb);

        // attn_out = P @ V : [1024,1024] @ [512,1024]^T -> f32 [1024,512]
        mfma_gemm<64, 64, false, false, false>
            <<<dim3(ND / 64, NS / 64, NB), 256, 0, stream>>>(
            pb, vT, nullptr, ao, nullptr,
            NS, NS, NS, ND, (long)NS * NS, (long)ND * NS, (long)NS * ND, 0.f);

        add_ln_kernel<<<dim3(NB * NS), 256, 0, stream>>>(
            x_cur, ao, ln1_g + (long)l * ND, ln1_b + (long)l * ND, x_cur, xb);

        // FFN1: [2048,512] @ [2048,512]^T + b, ReLU -> bf16 [2048,2048]
        mfma_gemm<128, 128, true, true, false>
            <<<dim3(NF / 128, (NB * NS) / 128, 1), 256, 0, stream>>>(
            xb, w1T + (long)l * NF * ND, ffn_b1 + (long)l * NF, hfb, nullptr,
            ND, ND, ND, NF, 0, 0, 0, 0.f);

        // FFN2: [2048,2048] @ [512,2048]^T + b -> f32 [2048,512]
        mfma_gemm<64, 64, false, false, false>
            <<<dim3(ND / 64, (NB * NS) / 64, 1), 256, 0, stream>>>(
            hfb, w2T + (long)l * ND * NF, ffn_b2 + (long)l * ND, ao, nullptr,
            NF, NF, NF, ND, 0, 0, 0, 0.f);

        add_ln_kernel<<<dim3(NB * NS), 256, 0, stream>>>(
            x_cur, ao, ln2_g + (long)l * ND, ln2_b + (long)l * ND, x_cur, xb);
    }

    add_ln_kernel<<<dim3(NB * NS), 256, 0, stream>>>(
        x_cur, nullptr, lnf_g, lnf_b, x_cur, nullptr);

    pool_kernel<<<dim3(ND / 256, NB), 256, 0, stream>>>(x_cur, pooled);

    fc_kernel<<<dim3((NC + 255) / 256, NB), 256, 0, stream>>>(pooled, fc_w, fc_b, out);
}